// Round 7
// baseline (613.215 us; speedup 1.0000x reference)
//
#include <hip/hip_runtime.h>
#include <math.h>

#define BB   128
#define NN   1024
#define BN   (BB*NN)          // 131072
#define EDG  (BB*8192)        // 1048576
#define K1C  820
#define K2C  656
#define TSEQ 19
#define HID  120
#define D1K  4816
#define D1CH 38               // ceil(4816/128)

// ---------------- reduction helper (128-thread block) ----------------
__device__ __forceinline__ float blockReduceSum128(float v, float* tmp2) {
#pragma unroll
  for (int o = 32; o > 0; o >>= 1) v += __shfl_down(v, o);
  int lane = threadIdx.x & 63, w = threadIdx.x >> 6;
  if (lane == 0) tmp2[w] = v;
  __syncthreads();
  float r = tmp2[0] + tmp2[1];
  __syncthreads();
  return r;
}

// ---------------- p-norm precompute ----------------
__global__ void k_pnorm(const float* __restrict__ p1, const float* __restrict__ p2,
                        float* __restrict__ invp) {
  __shared__ float tmp2[2];
  float a = p1[threadIdx.x], b = p2[threadIdx.x];
  float s1 = blockReduceSum128(a * a, tmp2);
  float s2 = blockReduceSum128(b * b, tmp2);
  if (threadIdx.x == 0) { invp[0] = 1.f / sqrtf(s1); invp[1] = 1.f / sqrtf(s2); }
}

// ---------------- layer-1 CSR build (per-graph, LDS, no global atomics) ----------------
// elist1 stores LOCAL src id (0..1023)
__global__ __launch_bounds__(1024) void k_csr1(const int* __restrict__ src,
                                               const int* __restrict__ dst,
                                               int* __restrict__ starts,
                                               int* __restrict__ cnt,
                                               int* __restrict__ elist) {
  __shared__ int h[1024];
  __shared__ int s[1024];
  int b = blockIdx.x, tid = threadIdx.x;
  h[tid] = 0;
  __syncthreads();
  int base = b * 8192, nb = b * 1024;
#pragma unroll
  for (int it = 0; it < 8; ++it) {
    int d = dst[base + it * 1024 + tid] - nb;
    atomicAdd(&h[d], 1);
  }
  __syncthreads();
  int v = h[tid];
  cnt[nb + tid] = v;
  s[tid] = v;
  __syncthreads();
  for (int o = 1; o < 1024; o <<= 1) {
    int t = (tid >= o) ? s[tid - o] : 0;
    __syncthreads();
    s[tid] += t;
    __syncthreads();
  }
  int st = s[tid] - v;                 // exclusive, local to graph
  starts[nb + tid] = base + st;
  h[tid] = st;                         // reuse as local cursor
  __syncthreads();
#pragma unroll
  for (int it = 0; it < 8; ++it) {
    int e = base + it * 1024 + tid;
    int d = dst[e] - nb;
    int pos = atomicAdd(&h[d], 1);
    elist[base + pos] = src[e] - nb;   // LOCAL src id
  }
}

// ---------------- layer-1 aggregate: LDS-staged x slice (16KB/graph) ----------------
__global__ __launch_bounds__(1024) void k_agg1(const int* __restrict__ starts,
                                               const int* __restrict__ cnt,
                                               const int* __restrict__ elist,
                                               const float* __restrict__ x,
                                               float* __restrict__ agg1) {
  __shared__ float4 xls4[1024];
  int b = blockIdx.x, tid = threadIdx.x;
  int nb = b * 1024;
  xls4[tid] = ((const float4*)x)[nb + tid];
  __syncthreads();
  const float* xls = (const float*)xls4;
  int rg = tid >> 2, lane = tid & 3;
#pragma unroll
  for (int it = 0; it < 4; ++it) {
    int r = rg + it * 256;
    int s0 = starts[nb + r], n = cnt[nb + r];
    float a0 = 0.f, a1 = 0.f;
    int j = 0;
    for (; j + 1 < n; j += 2) {
      int m0 = elist[s0 + j], m1 = elist[s0 + j + 1];
      a0 += xls[m0 * 4 + lane];
      a1 += xls[m1 * 4 + lane];
    }
    if (j < n) a0 += xls[elist[s0 + j] * 4 + lane];
    agg1[(size_t)(nb + r) * 4 + lane] = a0 + a1;
  }
}

// ---------------- h1 = relu(agg1@W1rel + x@W1root + b1); score1 fused ----------------
__global__ void k_h1(const float* __restrict__ x, const float* __restrict__ agg1,
                     const float* __restrict__ W1rel, const float* __restrict__ W1root,
                     const float* __restrict__ b1, const float* __restrict__ p1,
                     const float* __restrict__ invp,
                     float* __restrict__ h1, float* __restrict__ score1) {
  int tid = blockIdx.x * 256 + threadIdx.x;
  int r = tid >> 5, lane = tid & 31, f4 = lane * 4;
  float4 a = ((const float4*)agg1)[r];
  float4 xv = ((const float4*)x)[r];
  float o[4], dot = 0.f;
#pragma unroll
  for (int j = 0; j < 4; ++j) {
    int f = f4 + j;
    float acc = b1[f]
      + a.x * W1rel[f] + a.y * W1rel[128 + f] + a.z * W1rel[256 + f] + a.w * W1rel[384 + f]
      + xv.x * W1root[f] + xv.y * W1root[128 + f] + xv.z * W1root[256 + f] + xv.w * W1root[384 + f];
    o[j] = fmaxf(acc, 0.f);
    dot += o[j] * p1[f];
  }
  *(float4*)&h1[(size_t)r * 128 + f4] = make_float4(o[0], o[1], o[2], o[3]);
#pragma unroll
  for (int off = 16; off > 0; off >>= 1) dot += __shfl_down(dot, off, 32);
  if (lane == 0) score1[r] = tanhf(dot * invp[0]);
}

// ---------------- per-graph top-k via LDS bitonic sort (1024 slots) ----------------
__global__ void k_sort(const float* __restrict__ score, int n_per, int K,
                       int* __restrict__ perm, int* __restrict__ mapping) {
  __shared__ float s[1024];
  __shared__ int   id[1024];
  int b = blockIdx.x;
  const float* sc = score + (size_t)b * n_per;
  for (int i = threadIdx.x; i < 1024; i += blockDim.x) {
    if (i < n_per) { s[i] = sc[i]; id[i] = i; }
    else           { s[i] = -INFINITY; id[i] = 0x7fffffff; }
  }
  __syncthreads();
  for (int k = 2; k <= 1024; k <<= 1) {
    for (int j = k >> 1; j > 0; j >>= 1) {
      for (int i = threadIdx.x; i < 1024; i += blockDim.x) {
        int l = i ^ j;
        if (l > i) {
          float si = s[i], sl = s[l];
          int ii = id[i], il = id[l];
          bool iBeforeL = (si > sl) || (si == sl && ii < il);
          bool up = ((i & k) == 0);
          if (up ? (!iBeforeL) : iBeforeL) {
            s[i] = sl; s[l] = si; id[i] = il; id[l] = ii;
          }
        }
      }
      __syncthreads();
    }
  }
  for (int r = threadIdx.x; r < K; r += blockDim.x)
    perm[(size_t)b * K + r] = b * n_per + id[r];
  if (mapping) {
    for (int i = threadIdx.x; i < n_per; i += blockDim.x)
      mapping[(size_t)b * n_per + i] = -1;
    __syncthreads();
    for (int r = threadIdx.x; r < K; r += blockDim.x)
      mapping[(size_t)b * n_per + id[r]] = b * K + r;
  }
}

// ---------------- gather pooled rows (flat): xp[r] = h[perm[r]] * score[perm[r]] ----------------
__global__ void k_gather(const float* __restrict__ h, const float* __restrict__ score,
                         const int* __restrict__ perm, float* __restrict__ xp, int total) {
  int tid = blockIdx.x * 256 + threadIdx.x;
  if (tid >= total) return;
  int r = tid >> 5, q = tid & 31;
  int g = perm[r];
  float sc = score[g];
  float4 v = *(const float4*)&h[(size_t)g * 128 + q * 4];
  v.x *= sc; v.y *= sc; v.z *= sc; v.w *= sc;
  *(float4*)&xp[(size_t)r * 128 + q * 4] = v;
}

// ---------------- readout stage 1: partial [max||sum] over 64-row chunks ----------------
#define RCH 64
__global__ void k_readout1(const float* __restrict__ xp, float* __restrict__ pmax,
                           float* __restrict__ psum, int K, int nch) {
  int b = blockIdx.x / nch, c = blockIdx.x % nch, f = threadIdx.x;
  int r0 = c * RCH, r1 = min(r0 + RCH, K);
  const float* base = xp + ((size_t)b * K) * 128 + f;
  float mx = -INFINITY, sm = 0.f;
  for (int r = r0; r < r1; ++r) {
    float v = base[(size_t)r * 128];
    mx = fmaxf(mx, v); sm += v;
  }
  pmax[((size_t)b * nch + c) * 128 + f] = mx;
  psum[((size_t)b * nch + c) * 128 + f] = sm;
}

// ---------------- readout stage 2 ----------------
__global__ void k_readout2(const float* __restrict__ pmax, const float* __restrict__ psum,
                           float* __restrict__ xout, int K, int nch) {
  int b = blockIdx.x, f = threadIdx.x;
  float mx = -INFINITY, sm = 0.f;
  for (int c = 0; c < nch; ++c) {
    mx = fmaxf(mx, pmax[((size_t)b * nch + c) * 128 + f]);
    sm += psum[((size_t)b * nch + c) * 128 + f];
  }
  xout[b * 256 + f] = mx;
  xout[b * 256 + 128 + f] = sm / (float)K;
}

// ---------------- layer-2 filtered CSR (per-graph, LDS, no global atomics) ----------------
__global__ __launch_bounds__(1024) void k_csr2(const int* __restrict__ src,
                                               const int* __restrict__ dst,
                                               const int* __restrict__ map,
                                               int* __restrict__ starts2,
                                               int* __restrict__ cnt2,
                                               int* __restrict__ elist2) {
  __shared__ int mloc[8192];   // local kept dst per edge, -1 invalid
  __shared__ int msl[8192];    // local kept src per edge
  __shared__ int h[1024];
  __shared__ int s[1024];
  int g = blockIdx.x, tid = threadIdx.x;
  int base = g * 8192, nb2 = g * K1C;
  h[tid] = 0;
  __syncthreads();
#pragma unroll
  for (int it = 0; it < 8; ++it) {
    int e = base + it * 1024 + tid;
    int ms = map[src[e]], md = map[dst[e]];
    bool valid = (ms >= 0) && (md >= 0);
    int idx = it * 1024 + tid;
    int ml = valid ? (md - nb2) : -1;
    mloc[idx] = ml;
    msl[idx] = ms - nb2;
    if (valid) atomicAdd(&h[ml], 1);
  }
  __syncthreads();
  int v = (tid < K1C) ? h[tid] : 0;
  if (tid < K1C) cnt2[nb2 + tid] = v;
  s[tid] = v;
  __syncthreads();
  for (int o = 1; o < 1024; o <<= 1) {
    int t = (tid >= o) ? s[tid - o] : 0;
    __syncthreads();
    s[tid] += t;
    __syncthreads();
  }
  int st = s[tid] - v;
  if (tid < K1C) starts2[nb2 + tid] = base + st;
  h[tid] = st;                        // local cursor
  __syncthreads();
#pragma unroll
  for (int it = 0; it < 8; ++it) {
    int idx = it * 1024 + tid;
    int ml = mloc[idx];
    if (ml >= 0) {
      int pos = atomicAdd(&h[ml], 1);
      elist2[base + pos] = msl[idx];
    }
  }
}

// ---------------- layer-2 aggregate: LDS-staged xp1 f-chunk (105KB) ----------------
__global__ __launch_bounds__(1024) void k_agg2s(const int* __restrict__ starts2,
                                                const int* __restrict__ cnt2,
                                                const int* __restrict__ elist2,
                                                const float* __restrict__ xp1,
                                                float* __restrict__ agg2) {
  __shared__ float xls[K1C * 32];     // [row][32 feats] = 104,960 B
  int g = blockIdx.x >> 2, q = blockIdx.x & 3;
  int tid = threadIdx.x;
  int nb2 = g * K1C;
  for (int i = tid; i < K1C * 8; i += 1024) {
    int row = i >> 3, f4 = i & 7;
    ((float4*)xls)[i] = ((const float4*)xp1)[(size_t)(nb2 + row) * 32 + q * 8 + f4];
  }
  __syncthreads();
  int rg = tid >> 5, lane = tid & 31;  // 32 row-groups x 32 feats
  for (int r = rg; r < K1C; r += 32) {
    int s0 = starts2[nb2 + r], n = cnt2[nb2 + r];
    float a0 = 0.f, a1 = 0.f;
    int j = 0;
    for (; j + 1 < n; j += 2) {
      int m0 = elist2[s0 + j], m1 = elist2[s0 + j + 1];
      a0 += xls[m0 * 32 + lane];
      a1 += xls[m1 * 32 + lane];
    }
    if (j < n) a0 += xls[elist2[s0 + j] * 32 + lane];
    agg2[(size_t)(nb2 + r) * 128 + q * 32 + lane] = a0 + a1;
  }
}

// ---------------- h2 GEMM: 256x128 tile, 16x8/thread, merged K=256, fused score2 ----------------
// A transposed in LDS with stride 257 (4*257 % 32 == 4 -> worst 2-way, free).
__global__ __launch_bounds__(256, 2) void k_h2(
    const float* __restrict__ agg2, const float* __restrict__ xp1,
    const float* __restrict__ W2rel, const float* __restrict__ W2root,
    const float* __restrict__ b2, const float* __restrict__ p2,
    const float* __restrict__ invp, float* __restrict__ h2,
    float* __restrict__ score2) {
  __shared__ float As[32][257];      // [k][row], 32.9 KB
  __shared__ float Ws[32][132];      // [k][col], 16.9 KB
  int tid = threadIdx.x;
  int r0 = blockIdx.x * 256;
  int tx = tid & 15, ty = tid >> 4;  // cols {tx*4, 64+tx*4}, rows ty*16..ty*16+15
  float acc[16][8] = {};
  for (int ks = 0; ks < 8; ++ks) {
    const float* Asrc = (ks < 4) ? agg2 : xp1;
    const float* Wsrc = (ks < 4) ? W2rel : W2root;
    int kof = (ks & 3) * 32;
    // stage A transposed: 256 rows x 32 k = 2048 float4, 8/thread
#pragma unroll
    for (int l = 0; l < 8; ++l) {
      int idx = l * 256 + tid;
      int row = idx >> 3, kq = (idx & 7) * 4;
      float4 v = *(const float4*)&Asrc[(size_t)(r0 + row) * 128 + kof + kq];
      As[kq + 0][row] = v.x; As[kq + 1][row] = v.y;
      As[kq + 2][row] = v.z; As[kq + 3][row] = v.w;
    }
    // stage W: 32 k x 128 cols = 1024 float4, 4/thread
#pragma unroll
    for (int l = 0; l < 4; ++l) {
      int idx = l * 256 + tid;
      int kr = idx >> 5, c4 = (idx & 31) * 4;
      *(float4*)&Ws[kr][c4] = *(const float4*)&Wsrc[(size_t)(kof + kr) * 128 + c4];
    }
    __syncthreads();
#pragma unroll 4
    for (int kk = 0; kk < 32; ++kk) {
      const float* Ar = &As[kk][ty * 16];
      float4 a0 = *(const float4*)(Ar);
      float4 a1 = *(const float4*)(Ar + 4);
      float4 a2 = *(const float4*)(Ar + 8);
      float4 a3 = *(const float4*)(Ar + 12);
      float4 w0 = *(const float4*)&Ws[kk][tx * 4];
      float4 w1 = *(const float4*)&Ws[kk][64 + tx * 4];
      float av[16] = {a0.x, a0.y, a0.z, a0.w, a1.x, a1.y, a1.z, a1.w,
                      a2.x, a2.y, a2.z, a2.w, a3.x, a3.y, a3.z, a3.w};
      float wv[8] = {w0.x, w0.y, w0.z, w0.w, w1.x, w1.y, w1.z, w1.w};
#pragma unroll
      for (int i = 0; i < 16; ++i)
#pragma unroll
        for (int j = 0; j < 8; ++j) acc[i][j] += av[i] * wv[j];
    }
    __syncthreads();
  }
  float4 bb0 = *(const float4*)&b2[tx * 4];
  float4 bb1 = *(const float4*)&b2[64 + tx * 4];
  float4 pp0 = *(const float4*)&p2[tx * 4];
  float4 pp1 = *(const float4*)&p2[64 + tx * 4];
  float bbv[8] = {bb0.x, bb0.y, bb0.z, bb0.w, bb1.x, bb1.y, bb1.z, bb1.w};
  float pbv[8] = {pp0.x, pp0.y, pp0.z, pp0.w, pp1.x, pp1.y, pp1.z, pp1.w};
  float inv = invp[1];
#pragma unroll
  for (int i = 0; i < 16; ++i) {
    int row = r0 + ty * 16 + i;
    float o[8], dot = 0.f;
#pragma unroll
    for (int j = 0; j < 8; ++j) {
      o[j] = fmaxf(acc[i][j] + bbv[j], 0.f);
      dot += o[j] * pbv[j];
    }
    *(float4*)&h2[(size_t)row * 128 + tx * 4] = make_float4(o[0], o[1], o[2], o[3]);
    *(float4*)&h2[(size_t)row * 128 + 64 + tx * 4] = make_float4(o[4], o[5], o[6], o[7]);
#pragma unroll
    for (int off = 8; off > 0; off >>= 1) dot += __shfl_down(dot, off, 16);
    if (tx == 0) score2[row] = tanhf(dot * inv);
  }
}

// ---------------- target conv + relu + avgpool -> xs[t][b][o] ----------------
__global__ void k_conv(const float* __restrict__ target, const float* __restrict__ Wc,
                       const float* __restrict__ bc, float* __restrict__ xs) {
  int gb = blockIdx.x;               // B*19
  int b = gb / TSEQ, tt = gb % TSEQ;
  int o = threadIdx.x;               // 128
  __shared__ float tg[30][8];
  for (int i = threadIdx.x; i < 210; i += 128) {
    int ch = i / 7, u = i % 7;
    tg[ch][u] = target[((size_t)b * 30 + ch) * 101 + tt * 5 + u];
  }
  __syncthreads();
  const float* w = Wc + (size_t)o * 90;
  float acc5[5] = {0, 0, 0, 0, 0};
  for (int ch = 0; ch < 30; ++ch) {
    float w0 = w[ch * 3], w1 = w[ch * 3 + 1], w2 = w[ch * 3 + 2];
#pragma unroll
    for (int u = 0; u < 5; ++u)
      acc5[u] += tg[ch][u] * w0 + tg[ch][u + 1] * w1 + tg[ch][u + 2] * w2;
  }
  float bo = bc[o], s = 0.f;
#pragma unroll
  for (int u = 0; u < 5; ++u) s += fmaxf(acc5[u] + bo, 0.f);
  xs[((size_t)tt * BB + b) * 128 + o] = s * 0.2f;
}

// ---------------- gi = xs @ Wih^T + bih; 16 batches per block ----------------
#define GIB 16
__global__ __launch_bounds__(384) void k_gi(const float* __restrict__ xs,
                     const float* __restrict__ Wihf, const float* __restrict__ bihf,
                     const float* __restrict__ Wihb, const float* __restrict__ bihb,
                     float* __restrict__ gi) {
  int bg = blockIdx.x & 7;
  int t = (blockIdx.x >> 3) % TSEQ;
  int dir = blockIdx.x / (8 * TSEQ);
  int b0 = bg * GIB;
  __shared__ float xst[GIB][128];
  int tid = threadIdx.x;
  for (int i = tid; i < GIB * 128; i += 384) {
    int bb = i >> 7, k = i & 127;
    xst[bb][k] = xs[((size_t)t * BB + b0 + bb) * 128 + k];
  }
  __syncthreads();
  int j = tid;
  if (j < 360) {
    const float* W = (dir ? Wihb : Wihf) + (size_t)j * 128;
    float bias = (dir ? bihb : bihf)[j];
    float acc[GIB];
#pragma unroll
    for (int bb = 0; bb < GIB; ++bb) acc[bb] = bias;
#pragma unroll 4
    for (int k = 0; k < 128; ++k) {
      float w = W[k];
#pragma unroll
      for (int bb = 0; bb < GIB; ++bb) acc[bb] += xst[bb][k] * w;
    }
    size_t base = ((size_t)dir * TSEQ + t) * BB + b0;
#pragma unroll
    for (int bb = 0; bb < GIB; ++bb) gi[(base + bb) * 360 + j] = acc[bb];
  }
}

// ---------------- GRU recurrence: Whh rows held in REGISTERS, h via LDS broadcast ----------------
__global__ __launch_bounds__(384) void k_gru(const float* __restrict__ gi,
                      const float* __restrict__ Whhf, const float* __restrict__ bhhf,
                      const float* __restrict__ Whhb, const float* __restrict__ bhhb,
                      float* __restrict__ xc) {
  int pair = blockIdx.x & 63, dir = blockIdx.x >> 6;
  int b0 = pair * 2;
  const float* Whh = dir ? Whhb : Whhf;
  const float* bhh = dir ? bhhb : bhhf;
  __shared__ float h_sh[2][HID];
  __shared__ float g0[360], g1[360];
  int j = threadIdx.x;               // 384
  float wrow[HID];
  float bias = 0.f;
  if (j < 360) {
    const float4* W4 = (const float4*)(Whh + (size_t)j * HID);
#pragma unroll
    for (int k4 = 0; k4 < HID / 4; ++k4) {
      float4 w = W4[k4];
      wrow[k4 * 4 + 0] = w.x; wrow[k4 * 4 + 1] = w.y;
      wrow[k4 * 4 + 2] = w.z; wrow[k4 * 4 + 3] = w.w;
    }
    bias = bhh[j];
  }
  if (j < 2 * HID) h_sh[j / HID][j % HID] = 0.f;
  __syncthreads();
  for (int st = 0; st < TSEQ; ++st) {
    int tt = dir ? (TSEQ - 1 - st) : st;
    if (j < 360) {
      float a0 = bias, a1 = bias;
      const float4* h40 = (const float4*)h_sh[0];
      const float4* h41 = (const float4*)h_sh[1];
#pragma unroll
      for (int k4 = 0; k4 < HID / 4; ++k4) {
        float4 v0 = h40[k4];
        float4 v1 = h41[k4];
        a0 += wrow[k4*4+0]*v0.x + wrow[k4*4+1]*v0.y + wrow[k4*4+2]*v0.z + wrow[k4*4+3]*v0.w;
        a1 += wrow[k4*4+0]*v1.x + wrow[k4*4+1]*v1.y + wrow[k4*4+2]*v1.z + wrow[k4*4+3]*v1.w;
      }
      g0[j] = a0; g1[j] = a1;
    }
    __syncthreads();
    if (j < 2 * HID) {
      int bb = j / HID, th = j - bb * HID;
      const float* g = gi + (((size_t)dir * TSEQ + tt) * BB + (b0 + bb)) * 360;
      const float* gh = bb ? g1 : g0;
      float r  = 1.f / (1.f + expf(-(g[th]       + gh[th])));
      float z  = 1.f / (1.f + expf(-(g[120 + th] + gh[120 + th])));
      float ng = tanhf(g[240 + th] + r * gh[240 + th]);
      float hn = (1.f - z) * ng + z * h_sh[bb][th];
      h_sh[bb][th] = hn;
      xc[(size_t)(b0 + bb) * 4816 + 256 + (size_t)tt * 240 + dir * 120 + th] = hn;
    }
    __syncthreads();
  }
}

// ---------------- xg = x1 + x2 into xc[:, :256] ----------------
__global__ void k_xg(const float* __restrict__ x1, const float* __restrict__ x2,
                     float* __restrict__ xc) {
  int b = blockIdx.x, f = threadIdx.x;
  xc[(size_t)b * 4816 + f] = x1[b * 256 + f] + x2[b * 256 + f];
}

// ---------------- d1 partial GEMM ----------------
__global__ __launch_bounds__(128) void k_d1(const float* __restrict__ xc,
                                            const float* __restrict__ Wd1,
                                            float* __restrict__ part) {
  int c = blockIdx.x % D1CH;
  int rg = blockIdx.x / D1CH;
  int k0 = c * 128, kn = min(128, D1K - k0);
  __shared__ float xcs[8][128];
  int tid = threadIdx.x;
#pragma unroll
  for (int l = 0; l < 8; ++l) {
    int i = tid + l * 128;
    int r = i >> 7, k = i & 127;
    xcs[r][k] = (k < kn) ? xc[(size_t)(rg * 8 + r) * D1K + k0 + k] : 0.f;
  }
  __syncthreads();
  int j = tid;
  if (j < 102) {
    float acc[8] = {};
    for (int k = 0; k < kn; ++k) {
      float w = Wd1[(size_t)(k0 + k) * 102 + j];
#pragma unroll
      for (int r = 0; r < 8; ++r) acc[r] += xcs[r][k] * w;
    }
#pragma unroll
    for (int r = 0; r < 8; ++r)
      part[((size_t)(rg * 8 + r) * D1CH + c) * 102 + j] = acc[r];
  }
}

// ---------------- reduce partials + relu + d3 + log_softmax ----------------
__global__ void k_final2(const float* __restrict__ part, const float* __restrict__ bd1,
                         const float* __restrict__ Wd3, const float* __restrict__ bd3,
                         float* __restrict__ out) {
  __shared__ float tmp2[2];
  int b = blockIdx.x, j = threadIdx.x;
  float v = 0.f;
  if (j < 102) {
    float acc = bd1[j];
    for (int c = 0; c < D1CH; ++c) acc += part[((size_t)b * D1CH + c) * 102 + j];
    v = fmaxf(acc, 0.f);
  }
  float c0 = (j < 102) ? v * Wd3[j * 2] : 0.f;
  float c1 = (j < 102) ? v * Wd3[j * 2 + 1] : 0.f;
  float z0 = blockReduceSum128(c0, tmp2) + bd3[0];
  float z1 = blockReduceSum128(c1, tmp2) + bd3[1];
  if (j < 2) {
    float m = fmaxf(z0, z1);
    float lse = m + logf(expf(z0 - m) + expf(z1 - m));
    out[b * 2 + j] = (j == 0 ? z0 : z1) - lse;
  }
}

// ---------------- launch ----------------
extern "C" void kernel_launch(void* const* d_in, const int* in_sizes, int n_in,
                              void* d_out, int out_size, void* d_ws, size_t ws_size,
                              hipStream_t stream) {
  const float* x      = (const float*)d_in[0];
  const float* target = (const float*)d_in[1];
  const int*   esrc   = (const int*)d_in[2];
  const int*   edst   = (const int*)d_in[3];
  const float* W1rel  = (const float*)d_in[4];
  const float* W1root = (const float*)d_in[5];
  const float* b1     = (const float*)d_in[6];
  const float* p1     = (const float*)d_in[7];
  const float* W2rel  = (const float*)d_in[8];
  const float* W2root = (const float*)d_in[9];
  const float* b2     = (const float*)d_in[10];
  const float* p2     = (const float*)d_in[11];
  const float* Wc     = (const float*)d_in[12];
  const float* bc     = (const float*)d_in[13];
  const float* Wihf   = (const float*)d_in[14];
  const float* Whhf   = (const float*)d_in[15];
  const float* bihf   = (const float*)d_in[16];
  const float* bhhf   = (const float*)d_in[17];
  const float* Wihb   = (const float*)d_in[18];
  const float* Whhb   = (const float*)d_in[19];
  const float* bihb   = (const float*)d_in[20];
  const float* bhhb   = (const float*)d_in[21];
  const float* Wd1    = (const float*)d_in[22];
  const float* bd1    = (const float*)d_in[23];
  const float* Wd3    = (const float*)d_in[24];
  const float* bd3    = (const float*)d_in[25];
  float* out = (float*)d_out;

  char* wsb = (char*)d_ws;
  size_t off = 0;
  auto alloc = [&](size_t bytes) -> void* {
    void* p = wsb + off;
    off = (off + bytes + 255) & ~(size_t)255;
    return p;
  };
  float* regH    = (float*)alloc((size_t)BN * 128 * 4);   // h1 / agg2 / xp2 (64MB)
  float* agg1    = (float*)alloc((size_t)BN * 4 * 4);
  float* score1  = (float*)alloc((size_t)BN * 4);
  int*   perm1   = (int*)  alloc((size_t)BB * K1C * 4);
  int*   map1    = (int*)  alloc((size_t)BN * 4);
  float* xp1     = (float*)alloc((size_t)BB * K1C * 128 * 4);
  float* h2      = (float*)alloc((size_t)BB * K1C * 128 * 4);
  float* score2  = (float*)alloc((size_t)BB * K1C * 4);
  int*   perm2   = (int*)  alloc((size_t)BB * K2C * 4);
  float* x1      = (float*)alloc((size_t)BB * 256 * 4);
  float* x2      = (float*)alloc((size_t)BB * 256 * 4);
  float* invp    = (float*)alloc(256);
  float* xs      = (float*)alloc((size_t)TSEQ * BB * 128 * 4);
  float* gi      = (float*)alloc((size_t)2 * TSEQ * BB * 360 * 4);
  float* xc      = (float*)alloc((size_t)BB * 4816 * 4);
  int*   starts1 = (int*)  alloc((size_t)BN * 4);
  int*   cnt1    = (int*)  alloc((size_t)BN * 4);
  int*   elist1  = (int*)  alloc((size_t)EDG * 4);
  int*   starts2 = (int*)  alloc((size_t)BB * K1C * 4);
  int*   cnt2    = (int*)  alloc((size_t)BB * K1C * 4);
  int*   elist2  = (int*)  alloc((size_t)EDG * 4);
  float* pmax    = (float*)alloc((size_t)BB * 13 * 128 * 4);
  float* psum    = (float*)alloc((size_t)BB * 13 * 128 * 4);
  float* part    = (float*)alloc((size_t)BB * D1CH * 102 * 4);
  float* h1   = regH;
  float* agg2 = regH;
  float* xp2  = regH;

  k_pnorm<<<1, 128, 0, stream>>>(p1, p2, invp);
  k_csr1<<<BB, 1024, 0, stream>>>(esrc, edst, starts1, cnt1, elist1);

  // --- layer 1 ---
  k_agg1<<<BB, 1024, 0, stream>>>(starts1, cnt1, elist1, x, agg1);
  k_h1<<<BN * 32 / 256, 256, 0, stream>>>(x, agg1, W1rel, W1root, b1, p1, invp, h1, score1);
  k_sort<<<BB, 512, 0, stream>>>(score1, NN, K1C, perm1, map1);
  k_gather<<<(BB * K1C * 32) / 256, 256, 0, stream>>>(h1, score1, perm1, xp1, BB * K1C * 32);
  {
    int nch = (K1C + RCH - 1) / RCH;  // 13
    k_readout1<<<BB * nch, 128, 0, stream>>>(xp1, pmax, psum, K1C, nch);
    k_readout2<<<BB, 128, 0, stream>>>(pmax, psum, x1, K1C, nch);
  }

  // --- layer 2: filtered CSR + LDS-staged aggregate ---
  k_csr2<<<BB, 1024, 0, stream>>>(esrc, edst, map1, starts2, cnt2, elist2);
  k_agg2s<<<BB * 4, 1024, 0, stream>>>(starts2, cnt2, elist2, xp1, agg2);
  k_h2<<<(BB * K1C) / 256, 256, 0, stream>>>(agg2, xp1, W2rel, W2root, b2, p2, invp, h2, score2);
  k_sort<<<BB, 512, 0, stream>>>(score2, K1C, K2C, perm2, nullptr);
  k_gather<<<(BB * K2C * 32) / 256, 256, 0, stream>>>(h2, score2, perm2, xp2, BB * K2C * 32);
  {
    int nch = (K2C + RCH - 1) / RCH;  // 11
    k_readout1<<<BB * nch, 128, 0, stream>>>(xp2, pmax, psum, K2C, nch);
    k_readout2<<<BB, 128, 0, stream>>>(pmax, psum, x2, K2C, nch);
  }

  // --- target branch ---
  k_conv<<<BB * TSEQ, 128, 0, stream>>>(target, Wc, bc, xs);
  k_gi<<<2 * TSEQ * 8, 384, 0, stream>>>(xs, Wihf, bihf, Wihb, bihb, gi);
  k_gru<<<2 * 64, 384, 0, stream>>>(gi, Whhf, bhhf, Whhb, bhhb, xc);

  // --- head ---
  k_xg<<<BB, 256, 0, stream>>>(x1, x2, xc);
  k_d1<<<(BB / 8) * D1CH, 128, 0, stream>>>(xc, Wd1, part);
  k_final2<<<BB, 128, 0, stream>>>(part, bd1, Wd3, bd3, out);
}

// Round 8
// 509.864 us; speedup vs baseline: 1.2027x; 1.2027x over previous
//
#include <hip/hip_runtime.h>
#include <math.h>

#define BB   128
#define NN   1024
#define BN   (BB*NN)          // 131072
#define EDG  (BB*8192)        // 1048576
#define K1C  820
#define K2C  656
#define TSEQ 19
#define HID  120
#define D1K  4816
#define D1CH 38               // ceil(4816/128)

// ---------------- reduction helper (128-thread block) ----------------
__device__ __forceinline__ float blockReduceSum128(float v, float* tmp2) {
#pragma unroll
  for (int o = 32; o > 0; o >>= 1) v += __shfl_down(v, o);
  int lane = threadIdx.x & 63, w = threadIdx.x >> 6;
  if (lane == 0) tmp2[w] = v;
  __syncthreads();
  float r = tmp2[0] + tmp2[1];
  __syncthreads();
  return r;
}

// ---------------- p-norm precompute ----------------
__global__ void k_pnorm(const float* __restrict__ p1, const float* __restrict__ p2,
                        float* __restrict__ invp) {
  __shared__ float tmp2[2];
  float a = p1[threadIdx.x], b = p2[threadIdx.x];
  float s1 = blockReduceSum128(a * a, tmp2);
  float s2 = blockReduceSum128(b * b, tmp2);
  if (threadIdx.x == 0) { invp[0] = 1.f / sqrtf(s1); invp[1] = 1.f / sqrtf(s2); }
}

// ---------------- layer-1 CSR build (per-graph, LDS, no global atomics) ----------------
// elist1 stores LOCAL src id (0..1023)
__global__ __launch_bounds__(1024) void k_csr1(const int* __restrict__ src,
                                               const int* __restrict__ dst,
                                               int* __restrict__ starts,
                                               int* __restrict__ cnt,
                                               int* __restrict__ elist) {
  __shared__ int h[1024];
  __shared__ int s[1024];
  int b = blockIdx.x, tid = threadIdx.x;
  h[tid] = 0;
  __syncthreads();
  int base = b * 8192, nb = b * 1024;
#pragma unroll
  for (int it = 0; it < 8; ++it) {
    int d = dst[base + it * 1024 + tid] - nb;
    atomicAdd(&h[d], 1);
  }
  __syncthreads();
  int v = h[tid];
  cnt[nb + tid] = v;
  s[tid] = v;
  __syncthreads();
  for (int o = 1; o < 1024; o <<= 1) {
    int t = (tid >= o) ? s[tid - o] : 0;
    __syncthreads();
    s[tid] += t;
    __syncthreads();
  }
  int st = s[tid] - v;                 // exclusive, local to graph
  starts[nb + tid] = base + st;
  h[tid] = st;                         // reuse as local cursor
  __syncthreads();
#pragma unroll
  for (int it = 0; it < 8; ++it) {
    int e = base + it * 1024 + tid;
    int d = dst[e] - nb;
    int pos = atomicAdd(&h[d], 1);
    elist[base + pos] = src[e] - nb;   // LOCAL src id
  }
}

// ---------------- layer-1 aggregate: LDS-staged x slice (16KB/graph) ----------------
__global__ __launch_bounds__(1024) void k_agg1(const int* __restrict__ starts,
                                               const int* __restrict__ cnt,
                                               const int* __restrict__ elist,
                                               const float* __restrict__ x,
                                               float* __restrict__ agg1) {
  __shared__ float4 xls4[1024];
  int b = blockIdx.x, tid = threadIdx.x;
  int nb = b * 1024;
  xls4[tid] = ((const float4*)x)[nb + tid];
  __syncthreads();
  const float* xls = (const float*)xls4;
  int rg = tid >> 2, lane = tid & 3;
#pragma unroll
  for (int it = 0; it < 4; ++it) {
    int r = rg + it * 256;
    int s0 = starts[nb + r], n = cnt[nb + r];
    float a0 = 0.f, a1 = 0.f;
    int j = 0;
    for (; j + 1 < n; j += 2) {
      int m0 = elist[s0 + j], m1 = elist[s0 + j + 1];
      a0 += xls[m0 * 4 + lane];
      a1 += xls[m1 * 4 + lane];
    }
    if (j < n) a0 += xls[elist[s0 + j] * 4 + lane];
    agg1[(size_t)(nb + r) * 4 + lane] = a0 + a1;
  }
}

// ---------------- h1 = relu(agg1@W1rel + x@W1root + b1); score1 fused ----------------
__global__ void k_h1(const float* __restrict__ x, const float* __restrict__ agg1,
                     const float* __restrict__ W1rel, const float* __restrict__ W1root,
                     const float* __restrict__ b1, const float* __restrict__ p1,
                     const float* __restrict__ invp,
                     float* __restrict__ h1, float* __restrict__ score1) {
  int tid = blockIdx.x * 256 + threadIdx.x;
  int r = tid >> 5, lane = tid & 31, f4 = lane * 4;
  float4 a = ((const float4*)agg1)[r];
  float4 xv = ((const float4*)x)[r];
  float o[4], dot = 0.f;
#pragma unroll
  for (int j = 0; j < 4; ++j) {
    int f = f4 + j;
    float acc = b1[f]
      + a.x * W1rel[f] + a.y * W1rel[128 + f] + a.z * W1rel[256 + f] + a.w * W1rel[384 + f]
      + xv.x * W1root[f] + xv.y * W1root[128 + f] + xv.z * W1root[256 + f] + xv.w * W1root[384 + f];
    o[j] = fmaxf(acc, 0.f);
    dot += o[j] * p1[f];
  }
  *(float4*)&h1[(size_t)r * 128 + f4] = make_float4(o[0], o[1], o[2], o[3]);
#pragma unroll
  for (int off = 16; off > 0; off >>= 1) dot += __shfl_down(dot, off, 32);
  if (lane == 0) score1[r] = tanhf(dot * invp[0]);
}

// ---------------- per-graph top-k via LDS bitonic sort (1024 slots) ----------------
__global__ void k_sort(const float* __restrict__ score, int n_per, int K,
                       int* __restrict__ perm, int* __restrict__ mapping) {
  __shared__ float s[1024];
  __shared__ int   id[1024];
  int b = blockIdx.x;
  const float* sc = score + (size_t)b * n_per;
  for (int i = threadIdx.x; i < 1024; i += blockDim.x) {
    if (i < n_per) { s[i] = sc[i]; id[i] = i; }
    else           { s[i] = -INFINITY; id[i] = 0x7fffffff; }
  }
  __syncthreads();
  for (int k = 2; k <= 1024; k <<= 1) {
    for (int j = k >> 1; j > 0; j >>= 1) {
      for (int i = threadIdx.x; i < 1024; i += blockDim.x) {
        int l = i ^ j;
        if (l > i) {
          float si = s[i], sl = s[l];
          int ii = id[i], il = id[l];
          bool iBeforeL = (si > sl) || (si == sl && ii < il);
          bool up = ((i & k) == 0);
          if (up ? (!iBeforeL) : iBeforeL) {
            s[i] = sl; s[l] = si; id[i] = il; id[l] = ii;
          }
        }
      }
      __syncthreads();
    }
  }
  for (int r = threadIdx.x; r < K; r += blockDim.x)
    perm[(size_t)b * K + r] = b * n_per + id[r];
  if (mapping) {
    for (int i = threadIdx.x; i < n_per; i += blockDim.x)
      mapping[(size_t)b * n_per + i] = -1;
    __syncthreads();
    for (int r = threadIdx.x; r < K; r += blockDim.x)
      mapping[(size_t)b * n_per + id[r]] = b * K + r;
  }
}

// ---------------- gather pooled rows (flat): xp[r] = h[perm[r]] * score[perm[r]] ----------------
__global__ void k_gather(const float* __restrict__ h, const float* __restrict__ score,
                         const int* __restrict__ perm, float* __restrict__ xp, int total) {
  int tid = blockIdx.x * 256 + threadIdx.x;
  if (tid >= total) return;
  int r = tid >> 5, q = tid & 31;
  int g = perm[r];
  float sc = score[g];
  float4 v = *(const float4*)&h[(size_t)g * 128 + q * 4];
  v.x *= sc; v.y *= sc; v.z *= sc; v.w *= sc;
  *(float4*)&xp[(size_t)r * 128 + q * 4] = v;
}

// ---------------- readout stage 1: partial [max||sum] over 64-row chunks ----------------
#define RCH 64
__global__ void k_readout1(const float* __restrict__ xp, float* __restrict__ pmax,
                           float* __restrict__ psum, int K, int nch) {
  int b = blockIdx.x / nch, c = blockIdx.x % nch, f = threadIdx.x;
  int r0 = c * RCH, r1 = min(r0 + RCH, K);
  const float* base = xp + ((size_t)b * K) * 128 + f;
  float mx = -INFINITY, sm = 0.f;
  for (int r = r0; r < r1; ++r) {
    float v = base[(size_t)r * 128];
    mx = fmaxf(mx, v); sm += v;
  }
  pmax[((size_t)b * nch + c) * 128 + f] = mx;
  psum[((size_t)b * nch + c) * 128 + f] = sm;
}

// ---------------- readout stage 2 ----------------
__global__ void k_readout2(const float* __restrict__ pmax, const float* __restrict__ psum,
                           float* __restrict__ xout, int K, int nch) {
  int b = blockIdx.x, f = threadIdx.x;
  float mx = -INFINITY, sm = 0.f;
  for (int c = 0; c < nch; ++c) {
    mx = fmaxf(mx, pmax[((size_t)b * nch + c) * 128 + f]);
    sm += psum[((size_t)b * nch + c) * 128 + f];
  }
  xout[b * 256 + f] = mx;
  xout[b * 256 + 128 + f] = sm / (float)K;
}

// ---------------- layer-2 filtered CSR (per-graph, LDS, no global atomics) ----------------
__global__ __launch_bounds__(1024) void k_csr2(const int* __restrict__ src,
                                               const int* __restrict__ dst,
                                               const int* __restrict__ map,
                                               int* __restrict__ starts2,
                                               int* __restrict__ cnt2,
                                               int* __restrict__ elist2) {
  __shared__ int mloc[8192];   // local kept dst per edge, -1 invalid
  __shared__ int msl[8192];    // local kept src per edge
  __shared__ int h[1024];
  __shared__ int s[1024];
  int g = blockIdx.x, tid = threadIdx.x;
  int base = g * 8192, nb2 = g * K1C;
  h[tid] = 0;
  __syncthreads();
#pragma unroll
  for (int it = 0; it < 8; ++it) {
    int e = base + it * 1024 + tid;
    int ms = map[src[e]], md = map[dst[e]];
    bool valid = (ms >= 0) && (md >= 0);
    int idx = it * 1024 + tid;
    int ml = valid ? (md - nb2) : -1;
    mloc[idx] = ml;
    msl[idx] = ms - nb2;
    if (valid) atomicAdd(&h[ml], 1);
  }
  __syncthreads();
  int v = (tid < K1C) ? h[tid] : 0;
  if (tid < K1C) cnt2[nb2 + tid] = v;
  s[tid] = v;
  __syncthreads();
  for (int o = 1; o < 1024; o <<= 1) {
    int t = (tid >= o) ? s[tid - o] : 0;
    __syncthreads();
    s[tid] += t;
    __syncthreads();
  }
  int st = s[tid] - v;
  if (tid < K1C) starts2[nb2 + tid] = base + st;
  h[tid] = st;                        // local cursor
  __syncthreads();
#pragma unroll
  for (int it = 0; it < 8; ++it) {
    int idx = it * 1024 + tid;
    int ml = mloc[idx];
    if (ml >= 0) {
      int pos = atomicAdd(&h[ml], 1);
      elist2[base + pos] = msl[idx];
    }
  }
}

// ---------------- layer-2 aggregate: LDS-staged xp1 f-chunk (105KB) ----------------
__global__ __launch_bounds__(1024) void k_agg2s(const int* __restrict__ starts2,
                                                const int* __restrict__ cnt2,
                                                const int* __restrict__ elist2,
                                                const float* __restrict__ xp1,
                                                float* __restrict__ agg2) {
  __shared__ float xls[K1C * 32];     // [row][32 feats] = 104,960 B
  int g = blockIdx.x >> 2, q = blockIdx.x & 3;
  int tid = threadIdx.x;
  int nb2 = g * K1C;
  for (int i = tid; i < K1C * 8; i += 1024) {
    int row = i >> 3, f4 = i & 7;
    ((float4*)xls)[i] = ((const float4*)xp1)[(size_t)(nb2 + row) * 32 + q * 8 + f4];
  }
  __syncthreads();
  int rg = tid >> 5, lane = tid & 31;  // 32 row-groups x 32 feats
  for (int r = rg; r < K1C; r += 32) {
    int s0 = starts2[nb2 + r], n = cnt2[nb2 + r];
    float a0 = 0.f, a1 = 0.f;
    int j = 0;
    for (; j + 1 < n; j += 2) {
      int m0 = elist2[s0 + j], m1 = elist2[s0 + j + 1];
      a0 += xls[m0 * 32 + lane];
      a1 += xls[m1 * 32 + lane];
    }
    if (j < n) a0 += xls[elist2[s0 + j] * 32 + lane];
    agg2[(size_t)(nb2 + r) * 128 + q * 32 + lane] = a0 + a1;
  }
}

// ---------------- h2 GEMM: 128x128 tile, 8x8/thread, merged K=256, fused score2 ----------------
// A transposed in LDS with stride 129 -> store banks (kq+row)%32 = exact 2-way (free);
// W stride 132; reads are 16-lane broadcast, conflict-free.
#define ALDA 129
#define WLDA 132
__global__ __launch_bounds__(256, 3) void k_h2(
    const float* __restrict__ agg2, const float* __restrict__ xp1,
    const float* __restrict__ W2rel, const float* __restrict__ W2root,
    const float* __restrict__ b2, const float* __restrict__ p2,
    const float* __restrict__ invp, float* __restrict__ h2,
    float* __restrict__ score2) {
  __shared__ float As[32][ALDA];     // [k][row], 16.5 KB
  __shared__ float Ws[32][WLDA];     // [k][col], 16.9 KB
  int tid = threadIdx.x;
  int r0 = blockIdx.x * 128;
  int tx = tid & 15, ty = tid >> 4;  // cols {tx*4, 64+tx*4}, rows ty*8..ty*8+7
  float acc[8][8] = {};
  for (int ks = 0; ks < 8; ++ks) {
    const float* Asrc = (ks < 4) ? agg2 : xp1;
    const float* Wsrc = (ks < 4) ? W2rel : W2root;
    int kof = (ks & 3) * 32;
#pragma unroll
    for (int l = 0; l < 4; ++l) {
      int idx = l * 256 + tid;
      int row = idx >> 3, kq = (idx & 7) * 4;
      float4 v = *(const float4*)&Asrc[(size_t)(r0 + row) * 128 + kof + kq];
      As[kq + 0][row] = v.x; As[kq + 1][row] = v.y;
      As[kq + 2][row] = v.z; As[kq + 3][row] = v.w;
    }
#pragma unroll
    for (int l = 0; l < 4; ++l) {
      int idx = l * 256 + tid;
      int kr = idx >> 5, c4 = (idx & 31) * 4;
      *(float4*)&Ws[kr][c4] = *(const float4*)&Wsrc[(size_t)(kof + kr) * 128 + c4];
    }
    __syncthreads();
#pragma unroll 8
    for (int kk = 0; kk < 32; ++kk) {
      float4 a0 = *(const float4*)&As[kk][ty * 8];
      float4 a1 = *(const float4*)&As[kk][ty * 8 + 4];
      float4 w0 = *(const float4*)&Ws[kk][tx * 4];
      float4 w1 = *(const float4*)&Ws[kk][64 + tx * 4];
      float av[8] = {a0.x, a0.y, a0.z, a0.w, a1.x, a1.y, a1.z, a1.w};
      float wv[8] = {w0.x, w0.y, w0.z, w0.w, w1.x, w1.y, w1.z, w1.w};
#pragma unroll
      for (int i = 0; i < 8; ++i)
#pragma unroll
        for (int j = 0; j < 8; ++j) acc[i][j] += av[i] * wv[j];
    }
    __syncthreads();
  }
  float4 bb0 = *(const float4*)&b2[tx * 4];
  float4 bb1 = *(const float4*)&b2[64 + tx * 4];
  float4 pp0 = *(const float4*)&p2[tx * 4];
  float4 pp1 = *(const float4*)&p2[64 + tx * 4];
  float bbv[8] = {bb0.x, bb0.y, bb0.z, bb0.w, bb1.x, bb1.y, bb1.z, bb1.w};
  float pbv[8] = {pp0.x, pp0.y, pp0.z, pp0.w, pp1.x, pp1.y, pp1.z, pp1.w};
  float inv = invp[1];
#pragma unroll
  for (int i = 0; i < 8; ++i) {
    int row = r0 + ty * 8 + i;
    float o[8], dot = 0.f;
#pragma unroll
    for (int j = 0; j < 8; ++j) {
      o[j] = fmaxf(acc[i][j] + bbv[j], 0.f);
      dot += o[j] * pbv[j];
    }
    *(float4*)&h2[(size_t)row * 128 + tx * 4] = make_float4(o[0], o[1], o[2], o[3]);
    *(float4*)&h2[(size_t)row * 128 + 64 + tx * 4] = make_float4(o[4], o[5], o[6], o[7]);
#pragma unroll
    for (int off = 8; off > 0; off >>= 1) dot += __shfl_down(dot, off, 16);
    if (tx == 0) score2[row] = tanhf(dot * inv);
  }
}

// ---------------- target conv + relu + avgpool -> xs[t][b][o] ----------------
__global__ void k_conv(const float* __restrict__ target, const float* __restrict__ Wc,
                       const float* __restrict__ bc, float* __restrict__ xs) {
  int gb = blockIdx.x;               // B*19
  int b = gb / TSEQ, tt = gb % TSEQ;
  int o = threadIdx.x;               // 128
  __shared__ float tg[30][8];
  for (int i = threadIdx.x; i < 210; i += 128) {
    int ch = i / 7, u = i % 7;
    tg[ch][u] = target[((size_t)b * 30 + ch) * 101 + tt * 5 + u];
  }
  __syncthreads();
  const float* w = Wc + (size_t)o * 90;
  float acc5[5] = {0, 0, 0, 0, 0};
  for (int ch = 0; ch < 30; ++ch) {
    float w0 = w[ch * 3], w1 = w[ch * 3 + 1], w2 = w[ch * 3 + 2];
#pragma unroll
    for (int u = 0; u < 5; ++u)
      acc5[u] += tg[ch][u] * w0 + tg[ch][u + 1] * w1 + tg[ch][u + 2] * w2;
  }
  float bo = bc[o], s = 0.f;
#pragma unroll
  for (int u = 0; u < 5; ++u) s += fmaxf(acc5[u] + bo, 0.f);
  xs[((size_t)tt * BB + b) * 128 + o] = s * 0.2f;
}

// ---------------- gi = xs @ Wih^T + bih; 16 batches per block ----------------
#define GIB 16
__global__ __launch_bounds__(384) void k_gi(const float* __restrict__ xs,
                     const float* __restrict__ Wihf, const float* __restrict__ bihf,
                     const float* __restrict__ Wihb, const float* __restrict__ bihb,
                     float* __restrict__ gi) {
  int bg = blockIdx.x & 7;
  int t = (blockIdx.x >> 3) % TSEQ;
  int dir = blockIdx.x / (8 * TSEQ);
  int b0 = bg * GIB;
  __shared__ float xst[GIB][128];
  int tid = threadIdx.x;
  for (int i = tid; i < GIB * 128; i += 384) {
    int bb = i >> 7, k = i & 127;
    xst[bb][k] = xs[((size_t)t * BB + b0 + bb) * 128 + k];
  }
  __syncthreads();
  int j = tid;
  if (j < 360) {
    const float* W = (dir ? Wihb : Wihf) + (size_t)j * 128;
    float bias = (dir ? bihb : bihf)[j];
    float acc[GIB];
#pragma unroll
    for (int bb = 0; bb < GIB; ++bb) acc[bb] = bias;
#pragma unroll 4
    for (int k = 0; k < 128; ++k) {
      float w = W[k];
#pragma unroll
      for (int bb = 0; bb < GIB; ++bb) acc[bb] += xst[bb][k] * w;
    }
    size_t base = ((size_t)dir * TSEQ + t) * BB + b0;
#pragma unroll
    for (int bb = 0; bb < GIB; ++bb) gi[(base + bb) * 360 + j] = acc[bb];
  }
}

// ---------------- GRU recurrence: Whh rows held in REGISTERS, h via LDS broadcast ----------------
__global__ __launch_bounds__(384) void k_gru(const float* __restrict__ gi,
                      const float* __restrict__ Whhf, const float* __restrict__ bhhf,
                      const float* __restrict__ Whhb, const float* __restrict__ bhhb,
                      float* __restrict__ xc) {
  int pair = blockIdx.x & 63, dir = blockIdx.x >> 6;
  int b0 = pair * 2;
  const float* Whh = dir ? Whhb : Whhf;
  const float* bhh = dir ? bhhb : bhhf;
  __shared__ float h_sh[2][HID];
  __shared__ float g0[360], g1[360];
  int j = threadIdx.x;               // 384
  float wrow[HID];
  float bias = 0.f;
  if (j < 360) {
    const float4* W4 = (const float4*)(Whh + (size_t)j * HID);
#pragma unroll
    for (int k4 = 0; k4 < HID / 4; ++k4) {
      float4 w = W4[k4];
      wrow[k4 * 4 + 0] = w.x; wrow[k4 * 4 + 1] = w.y;
      wrow[k4 * 4 + 2] = w.z; wrow[k4 * 4 + 3] = w.w;
    }
    bias = bhh[j];
  }
  if (j < 2 * HID) h_sh[j / HID][j % HID] = 0.f;
  __syncthreads();
  for (int st = 0; st < TSEQ; ++st) {
    int tt = dir ? (TSEQ - 1 - st) : st;
    if (j < 360) {
      float a0 = bias, a1 = bias;
      const float4* h40 = (const float4*)h_sh[0];
      const float4* h41 = (const float4*)h_sh[1];
#pragma unroll
      for (int k4 = 0; k4 < HID / 4; ++k4) {
        float4 v0 = h40[k4];
        float4 v1 = h41[k4];
        a0 += wrow[k4*4+0]*v0.x + wrow[k4*4+1]*v0.y + wrow[k4*4+2]*v0.z + wrow[k4*4+3]*v0.w;
        a1 += wrow[k4*4+0]*v1.x + wrow[k4*4+1]*v1.y + wrow[k4*4+2]*v1.z + wrow[k4*4+3]*v1.w;
      }
      g0[j] = a0; g1[j] = a1;
    }
    __syncthreads();
    if (j < 2 * HID) {
      int bb = j / HID, th = j - bb * HID;
      const float* g = gi + (((size_t)dir * TSEQ + tt) * BB + (b0 + bb)) * 360;
      const float* gh = bb ? g1 : g0;
      float r  = 1.f / (1.f + expf(-(g[th]       + gh[th])));
      float z  = 1.f / (1.f + expf(-(g[120 + th] + gh[120 + th])));
      float ng = tanhf(g[240 + th] + r * gh[240 + th]);
      float hn = (1.f - z) * ng + z * h_sh[bb][th];
      h_sh[bb][th] = hn;
      xc[(size_t)(b0 + bb) * 4816 + 256 + (size_t)tt * 240 + dir * 120 + th] = hn;
    }
    __syncthreads();
  }
}

// ---------------- xg = x1 + x2 into xc[:, :256] ----------------
__global__ void k_xg(const float* __restrict__ x1, const float* __restrict__ x2,
                     float* __restrict__ xc) {
  int b = blockIdx.x, f = threadIdx.x;
  xc[(size_t)b * 4816 + f] = x1[b * 256 + f] + x2[b * 256 + f];
}

// ---------------- d1 partial GEMM ----------------
__global__ __launch_bounds__(128) void k_d1(const float* __restrict__ xc,
                                            const float* __restrict__ Wd1,
                                            float* __restrict__ part) {
  int c = blockIdx.x % D1CH;
  int rg = blockIdx.x / D1CH;
  int k0 = c * 128, kn = min(128, D1K - k0);
  __shared__ float xcs[8][128];
  int tid = threadIdx.x;
#pragma unroll
  for (int l = 0; l < 8; ++l) {
    int i = tid + l * 128;
    int r = i >> 7, k = i & 127;
    xcs[r][k] = (k < kn) ? xc[(size_t)(rg * 8 + r) * D1K + k0 + k] : 0.f;
  }
  __syncthreads();
  int j = tid;
  if (j < 102) {
    float acc[8] = {};
    for (int k = 0; k < kn; ++k) {
      float w = Wd1[(size_t)(k0 + k) * 102 + j];
#pragma unroll
      for (int r = 0; r < 8; ++r) acc[r] += xcs[r][k] * w;
    }
#pragma unroll
    for (int r = 0; r < 8; ++r)
      part[((size_t)(rg * 8 + r) * D1CH + c) * 102 + j] = acc[r];
  }
}

// ---------------- reduce partials + relu + d3 + log_softmax ----------------
__global__ void k_final2(const float* __restrict__ part, const float* __restrict__ bd1,
                         const float* __restrict__ Wd3, const float* __restrict__ bd3,
                         float* __restrict__ out) {
  __shared__ float tmp2[2];
  int b = blockIdx.x, j = threadIdx.x;
  float v = 0.f;
  if (j < 102) {
    float acc = bd1[j];
    for (int c = 0; c < D1CH; ++c) acc += part[((size_t)b * D1CH + c) * 102 + j];
    v = fmaxf(acc, 0.f);
  }
  float c0 = (j < 102) ? v * Wd3[j * 2] : 0.f;
  float c1 = (j < 102) ? v * Wd3[j * 2 + 1] : 0.f;
  float z0 = blockReduceSum128(c0, tmp2) + bd3[0];
  float z1 = blockReduceSum128(c1, tmp2) + bd3[1];
  if (j < 2) {
    float m = fmaxf(z0, z1);
    float lse = m + logf(expf(z0 - m) + expf(z1 - m));
    out[b * 2 + j] = (j == 0 ? z0 : z1) - lse;
  }
}

// ---------------- launch ----------------
extern "C" void kernel_launch(void* const* d_in, const int* in_sizes, int n_in,
                              void* d_out, int out_size, void* d_ws, size_t ws_size,
                              hipStream_t stream) {
  const float* x      = (const float*)d_in[0];
  const float* target = (const float*)d_in[1];
  const int*   esrc   = (const int*)d_in[2];
  const int*   edst   = (const int*)d_in[3];
  const float* W1rel  = (const float*)d_in[4];
  const float* W1root = (const float*)d_in[5];
  const float* b1     = (const float*)d_in[6];
  const float* p1     = (const float*)d_in[7];
  const float* W2rel  = (const float*)d_in[8];
  const float* W2root = (const float*)d_in[9];
  const float* b2     = (const float*)d_in[10];
  const float* p2     = (const float*)d_in[11];
  const float* Wc     = (const float*)d_in[12];
  const float* bc     = (const float*)d_in[13];
  const float* Wihf   = (const float*)d_in[14];
  const float* Whhf   = (const float*)d_in[15];
  const float* bihf   = (const float*)d_in[16];
  const float* bhhf   = (const float*)d_in[17];
  const float* Wihb   = (const float*)d_in[18];
  const float* Whhb   = (const float*)d_in[19];
  const float* bihb   = (const float*)d_in[20];
  const float* bhhb   = (const float*)d_in[21];
  const float* Wd1    = (const float*)d_in[22];
  const float* bd1    = (const float*)d_in[23];
  const float* Wd3    = (const float*)d_in[24];
  const float* bd3    = (const float*)d_in[25];
  float* out = (float*)d_out;

  char* wsb = (char*)d_ws;
  size_t off = 0;
  auto alloc = [&](size_t bytes) -> void* {
    void* p = wsb + off;
    off = (off + bytes + 255) & ~(size_t)255;
    return p;
  };
  float* regH    = (float*)alloc((size_t)BN * 128 * 4);   // h1 / agg2 / xp2 (64MB)
  float* agg1    = (float*)alloc((size_t)BN * 4 * 4);
  float* score1  = (float*)alloc((size_t)BN * 4);
  int*   perm1   = (int*)  alloc((size_t)BB * K1C * 4);
  int*   map1    = (int*)  alloc((size_t)BN * 4);
  float* xp1     = (float*)alloc((size_t)BB * K1C * 128 * 4);
  float* h2      = (float*)alloc((size_t)BB * K1C * 128 * 4);
  float* score2  = (float*)alloc((size_t)BB * K1C * 4);
  int*   perm2   = (int*)  alloc((size_t)BB * K2C * 4);
  float* x1      = (float*)alloc((size_t)BB * 256 * 4);
  float* x2      = (float*)alloc((size_t)BB * 256 * 4);
  float* invp    = (float*)alloc(256);
  float* xs      = (float*)alloc((size_t)TSEQ * BB * 128 * 4);
  float* gi      = (float*)alloc((size_t)2 * TSEQ * BB * 360 * 4);
  float* xc      = (float*)alloc((size_t)BB * 4816 * 4);
  int*   starts1 = (int*)  alloc((size_t)BN * 4);
  int*   cnt1    = (int*)  alloc((size_t)BN * 4);
  int*   elist1  = (int*)  alloc((size_t)EDG * 4);
  int*   starts2 = (int*)  alloc((size_t)BB * K1C * 4);
  int*   cnt2    = (int*)  alloc((size_t)BB * K1C * 4);
  int*   elist2  = (int*)  alloc((size_t)EDG * 4);
  float* pmax    = (float*)alloc((size_t)BB * 13 * 128 * 4);
  float* psum    = (float*)alloc((size_t)BB * 13 * 128 * 4);
  float* part    = (float*)alloc((size_t)BB * D1CH * 102 * 4);
  float* h1   = regH;
  float* agg2 = regH;
  float* xp2  = regH;

  k_pnorm<<<1, 128, 0, stream>>>(p1, p2, invp);
  k_csr1<<<BB, 1024, 0, stream>>>(esrc, edst, starts1, cnt1, elist1);

  // --- layer 1 ---
  k_agg1<<<BB, 1024, 0, stream>>>(starts1, cnt1, elist1, x, agg1);
  k_h1<<<BN * 32 / 256, 256, 0, stream>>>(x, agg1, W1rel, W1root, b1, p1, invp, h1, score1);
  k_sort<<<BB, 512, 0, stream>>>(score1, NN, K1C, perm1, map1);
  k_gather<<<(BB * K1C * 32) / 256, 256, 0, stream>>>(h1, score1, perm1, xp1, BB * K1C * 32);
  {
    int nch = (K1C + RCH - 1) / RCH;  // 13
    k_readout1<<<BB * nch, 128, 0, stream>>>(xp1, pmax, psum, K1C, nch);
    k_readout2<<<BB, 128, 0, stream>>>(pmax, psum, x1, K1C, nch);
  }

  // --- layer 2: filtered CSR + LDS-staged aggregate ---
  k_csr2<<<BB, 1024, 0, stream>>>(esrc, edst, map1, starts2, cnt2, elist2);
  k_agg2s<<<BB * 4, 1024, 0, stream>>>(starts2, cnt2, elist2, xp1, agg2);
  k_h2<<<(BB * K1C) / 128, 256, 0, stream>>>(agg2, xp1, W2rel, W2root, b2, p2, invp, h2, score2);
  k_sort<<<BB, 512, 0, stream>>>(score2, K1C, K2C, perm2, nullptr);
  k_gather<<<(BB * K2C * 32) / 256, 256, 0, stream>>>(h2, score2, perm2, xp2, BB * K2C * 32);
  {
    int nch = (K2C + RCH - 1) / RCH;  // 11
    k_readout1<<<BB * nch, 128, 0, stream>>>(xp2, pmax, psum, K2C, nch);
    k_readout2<<<BB, 128, 0, stream>>>(pmax, psum, x2, K2C, nch);
  }

  // --- target branch ---
  k_conv<<<BB * TSEQ, 128, 0, stream>>>(target, Wc, bc, xs);
  k_gi<<<2 * TSEQ * 8, 384, 0, stream>>>(xs, Wihf, bihf, Wihb, bihb, gi);
  k_gru<<<2 * 64, 384, 0, stream>>>(gi, Whhf, bhhf, Whhb, bhhb, xc);

  // --- head ---
  k_xg<<<BB, 256, 0, stream>>>(x1, x2, xc);
  k_d1<<<(BB / 8) * D1CH, 128, 0, stream>>>(xc, Wd1, part);
  k_final2<<<BB, 128, 0, stream>>>(part, bd1, Wd3, bd3, out);
}

// Round 9
// 484.658 us; speedup vs baseline: 1.2653x; 1.0520x over previous
//
#include <hip/hip_runtime.h>
#include <math.h>

#define BB   128
#define NN   1024
#define BN   (BB*NN)          // 131072
#define EDG  (BB*8192)        // 1048576
#define K1C  820
#define K2C  656
#define TSEQ 19
#define HID  120
#define D1K  4816
#define D1CH 38               // ceil(4816/128)

// ---------------- reduction helper (128-thread block) ----------------
__device__ __forceinline__ float blockReduceSum128(float v, float* tmp2) {
#pragma unroll
  for (int o = 32; o > 0; o >>= 1) v += __shfl_down(v, o);
  int lane = threadIdx.x & 63, w = threadIdx.x >> 6;
  if (lane == 0) tmp2[w] = v;
  __syncthreads();
  float r = tmp2[0] + tmp2[1];
  __syncthreads();
  return r;
}

// ---------------- p-norm precompute ----------------
__global__ void k_pnorm(const float* __restrict__ p1, const float* __restrict__ p2,
                        float* __restrict__ invp) {
  __shared__ float tmp2[2];
  float a = p1[threadIdx.x], b = p2[threadIdx.x];
  float s1 = blockReduceSum128(a * a, tmp2);
  float s2 = blockReduceSum128(b * b, tmp2);
  if (threadIdx.x == 0) { invp[0] = 1.f / sqrtf(s1); invp[1] = 1.f / sqrtf(s2); }
}

// ---------------- layer-1 CSR build (per-graph, LDS, no global atomics) ----------------
// elist1 stores LOCAL src id (0..1023)
__global__ __launch_bounds__(1024) void k_csr1(const int* __restrict__ src,
                                               const int* __restrict__ dst,
                                               int* __restrict__ starts,
                                               int* __restrict__ cnt,
                                               int* __restrict__ elist) {
  __shared__ int h[1024];
  __shared__ int s[1024];
  int b = blockIdx.x, tid = threadIdx.x;
  h[tid] = 0;
  __syncthreads();
  int base = b * 8192, nb = b * 1024;
#pragma unroll
  for (int it = 0; it < 8; ++it) {
    int d = dst[base + it * 1024 + tid] - nb;
    atomicAdd(&h[d], 1);
  }
  __syncthreads();
  int v = h[tid];
  cnt[nb + tid] = v;
  s[tid] = v;
  __syncthreads();
  for (int o = 1; o < 1024; o <<= 1) {
    int t = (tid >= o) ? s[tid - o] : 0;
    __syncthreads();
    s[tid] += t;
    __syncthreads();
  }
  int st = s[tid] - v;                 // exclusive, local to graph
  starts[nb + tid] = base + st;
  h[tid] = st;                         // reuse as local cursor
  __syncthreads();
#pragma unroll
  for (int it = 0; it < 8; ++it) {
    int e = base + it * 1024 + tid;
    int d = dst[e] - nb;
    int pos = atomicAdd(&h[d], 1);
    elist[base + pos] = src[e] - nb;   // LOCAL src id
  }
}

// ---------------- layer-1 aggregate: LDS-staged x slice (16KB/graph) ----------------
__global__ __launch_bounds__(1024) void k_agg1(const int* __restrict__ starts,
                                               const int* __restrict__ cnt,
                                               const int* __restrict__ elist,
                                               const float* __restrict__ x,
                                               float* __restrict__ agg1) {
  __shared__ float4 xls4[1024];
  int b = blockIdx.x, tid = threadIdx.x;
  int nb = b * 1024;
  xls4[tid] = ((const float4*)x)[nb + tid];
  __syncthreads();
  const float* xls = (const float*)xls4;
  int rg = tid >> 2, lane = tid & 3;
#pragma unroll
  for (int it = 0; it < 4; ++it) {
    int r = rg + it * 256;
    int s0 = starts[nb + r], n = cnt[nb + r];
    float a0 = 0.f, a1 = 0.f;
    int j = 0;
    for (; j + 1 < n; j += 2) {
      int m0 = elist[s0 + j], m1 = elist[s0 + j + 1];
      a0 += xls[m0 * 4 + lane];
      a1 += xls[m1 * 4 + lane];
    }
    if (j < n) a0 += xls[elist[s0 + j] * 4 + lane];
    agg1[(size_t)(nb + r) * 4 + lane] = a0 + a1;
  }
}

// ---------------- h1 = relu(agg1@W1rel + x@W1root + b1); score1 fused ----------------
__global__ void k_h1(const float* __restrict__ x, const float* __restrict__ agg1,
                     const float* __restrict__ W1rel, const float* __restrict__ W1root,
                     const float* __restrict__ b1, const float* __restrict__ p1,
                     const float* __restrict__ invp,
                     float* __restrict__ h1, float* __restrict__ score1) {
  int tid = blockIdx.x * 256 + threadIdx.x;
  int r = tid >> 5, lane = tid & 31, f4 = lane * 4;
  float4 a = ((const float4*)agg1)[r];
  float4 xv = ((const float4*)x)[r];
  float o[4], dot = 0.f;
#pragma unroll
  for (int j = 0; j < 4; ++j) {
    int f = f4 + j;
    float acc = b1[f]
      + a.x * W1rel[f] + a.y * W1rel[128 + f] + a.z * W1rel[256 + f] + a.w * W1rel[384 + f]
      + xv.x * W1root[f] + xv.y * W1root[128 + f] + xv.z * W1root[256 + f] + xv.w * W1root[384 + f];
    o[j] = fmaxf(acc, 0.f);
    dot += o[j] * p1[f];
  }
  *(float4*)&h1[(size_t)r * 128 + f4] = make_float4(o[0], o[1], o[2], o[3]);
#pragma unroll
  for (int off = 16; off > 0; off >>= 1) dot += __shfl_down(dot, off, 32);
  if (lane == 0) score1[r] = tanhf(dot * invp[0]);
}

// ---------------- per-graph top-k via LDS bitonic sort (1024 slots) ----------------
__global__ void k_sort(const float* __restrict__ score, int n_per, int K,
                       int* __restrict__ perm, int* __restrict__ mapping) {
  __shared__ float s[1024];
  __shared__ int   id[1024];
  int b = blockIdx.x;
  const float* sc = score + (size_t)b * n_per;
  for (int i = threadIdx.x; i < 1024; i += blockDim.x) {
    if (i < n_per) { s[i] = sc[i]; id[i] = i; }
    else           { s[i] = -INFINITY; id[i] = 0x7fffffff; }
  }
  __syncthreads();
  for (int k = 2; k <= 1024; k <<= 1) {
    for (int j = k >> 1; j > 0; j >>= 1) {
      for (int i = threadIdx.x; i < 1024; i += blockDim.x) {
        int l = i ^ j;
        if (l > i) {
          float si = s[i], sl = s[l];
          int ii = id[i], il = id[l];
          bool iBeforeL = (si > sl) || (si == sl && ii < il);
          bool up = ((i & k) == 0);
          if (up ? (!iBeforeL) : iBeforeL) {
            s[i] = sl; s[l] = si; id[i] = il; id[l] = ii;
          }
        }
      }
      __syncthreads();
    }
  }
  for (int r = threadIdx.x; r < K; r += blockDim.x)
    perm[(size_t)b * K + r] = b * n_per + id[r];
  if (mapping) {
    for (int i = threadIdx.x; i < n_per; i += blockDim.x)
      mapping[(size_t)b * n_per + i] = -1;
    __syncthreads();
    for (int r = threadIdx.x; r < K; r += blockDim.x)
      mapping[(size_t)b * n_per + id[r]] = b * K + r;
  }
}

// ---------------- fused gather(+scale) + partial readout over 64-row chunks ----------------
// xp may be null (layer 2: no materialization needed)
#define RCH 64
__global__ void k_gatherread(const float* __restrict__ h, const float* __restrict__ score,
                             const int* __restrict__ perm, float* __restrict__ xp,
                             float* __restrict__ pmax, float* __restrict__ psum,
                             int K, int nch) {
  int b = blockIdx.x / nch, c = blockIdx.x % nch, f = threadIdx.x;  // 128 threads
  int r0 = c * RCH, r1 = min(r0 + RCH, K);
  float mx = -INFINITY, sm = 0.f;
  if (xp) {
    for (int r = r0; r < r1; ++r) {
      int g = perm[(size_t)b * K + r];
      float v = h[(size_t)g * 128 + f] * score[g];
      xp[((size_t)b * K + r) * 128 + f] = v;
      mx = fmaxf(mx, v); sm += v;
    }
  } else {
    for (int r = r0; r < r1; ++r) {
      int g = perm[(size_t)b * K + r];
      float v = h[(size_t)g * 128 + f] * score[g];
      mx = fmaxf(mx, v); sm += v;
    }
  }
  pmax[((size_t)b * nch + c) * 128 + f] = mx;
  psum[((size_t)b * nch + c) * 128 + f] = sm;
}

// ---------------- readout stage 2 ----------------
__global__ void k_readout2(const float* __restrict__ pmax, const float* __restrict__ psum,
                           float* __restrict__ xout, int K, int nch) {
  int b = blockIdx.x, f = threadIdx.x;
  float mx = -INFINITY, sm = 0.f;
  for (int c = 0; c < nch; ++c) {
    mx = fmaxf(mx, pmax[((size_t)b * nch + c) * 128 + f]);
    sm += psum[((size_t)b * nch + c) * 128 + f];
  }
  xout[b * 256 + f] = mx;
  xout[b * 256 + 128 + f] = sm / (float)K;
}

// ---------------- layer-2 filtered CSR (per-graph, LDS, no global atomics) ----------------
__global__ __launch_bounds__(1024) void k_csr2(const int* __restrict__ src,
                                               const int* __restrict__ dst,
                                               const int* __restrict__ map,
                                               int* __restrict__ starts2,
                                               int* __restrict__ cnt2,
                                               int* __restrict__ elist2) {
  __shared__ int mloc[8192];   // local kept dst per edge, -1 invalid
  __shared__ int msl[8192];    // local kept src per edge
  __shared__ int h[1024];
  __shared__ int s[1024];
  int g = blockIdx.x, tid = threadIdx.x;
  int base = g * 8192, nb2 = g * K1C;
  h[tid] = 0;
  __syncthreads();
#pragma unroll
  for (int it = 0; it < 8; ++it) {
    int e = base + it * 1024 + tid;
    int ms = map[src[e]], md = map[dst[e]];
    bool valid = (ms >= 0) && (md >= 0);
    int idx = it * 1024 + tid;
    int ml = valid ? (md - nb2) : -1;
    mloc[idx] = ml;
    msl[idx] = ms - nb2;
    if (valid) atomicAdd(&h[ml], 1);
  }
  __syncthreads();
  int v = (tid < K1C) ? h[tid] : 0;
  if (tid < K1C) cnt2[nb2 + tid] = v;
  s[tid] = v;
  __syncthreads();
  for (int o = 1; o < 1024; o <<= 1) {
    int t = (tid >= o) ? s[tid - o] : 0;
    __syncthreads();
    s[tid] += t;
    __syncthreads();
  }
  int st = s[tid] - v;
  if (tid < K1C) starts2[nb2 + tid] = base + st;
  h[tid] = st;                        // local cursor
  __syncthreads();
#pragma unroll
  for (int it = 0; it < 8; ++it) {
    int idx = it * 1024 + tid;
    int ml = mloc[idx];
    if (ml >= 0) {
      int pos = atomicAdd(&h[ml], 1);
      elist2[base + pos] = msl[idx];
    }
  }
}

// ---------------- layer-2 aggregate: LDS-staged xp1 f-chunk (105KB) ----------------
__global__ __launch_bounds__(1024) void k_agg2s(const int* __restrict__ starts2,
                                                const int* __restrict__ cnt2,
                                                const int* __restrict__ elist2,
                                                const float* __restrict__ xp1,
                                                float* __restrict__ agg2) {
  __shared__ float xls[K1C * 32];     // [row][32 feats] = 104,960 B
  int g = blockIdx.x >> 2, q = blockIdx.x & 3;
  int tid = threadIdx.x;
  int nb2 = g * K1C;
  for (int i = tid; i < K1C * 8; i += 1024) {
    int row = i >> 3, f4 = i & 7;
    ((float4*)xls)[i] = ((const float4*)xp1)[(size_t)(nb2 + row) * 32 + q * 8 + f4];
  }
  __syncthreads();
  int rg = tid >> 5, lane = tid & 31;  // 32 row-groups x 32 feats
  for (int r = rg; r < K1C; r += 32) {
    int s0 = starts2[nb2 + r], n = cnt2[nb2 + r];
    float a0 = 0.f, a1 = 0.f;
    int j = 0;
    for (; j + 1 < n; j += 2) {
      int m0 = elist2[s0 + j], m1 = elist2[s0 + j + 1];
      a0 += xls[m0 * 32 + lane];
      a1 += xls[m1 * 32 + lane];
    }
    if (j < n) a0 += xls[elist2[s0 + j] * 32 + lane];
    agg2[(size_t)(nb2 + r) * 128 + q * 32 + lane] = a0 + a1;
  }
}

// ---------------- h2 GEMM: 128x128 tile, 8x8/thread, BK=16, 4 blocks/CU ----------------
// A transposed in LDS stride 130 -> store banks (2(kq+c)+row)%32 = 2-way (free);
// W stride 132; reads broadcast, conflict-free. 16 K-chunks; cross-block overlap
// hides the per-chunk barrier drains (16 waves/CU).
#define ALDA 130
#define WLDA 132
__global__ __launch_bounds__(256, 4) void k_h2(
    const float* __restrict__ agg2, const float* __restrict__ xp1,
    const float* __restrict__ W2rel, const float* __restrict__ W2root,
    const float* __restrict__ b2, const float* __restrict__ p2,
    const float* __restrict__ invp, float* __restrict__ h2,
    float* __restrict__ score2) {
  __shared__ float As[16][ALDA];     // [k][row], 8.3 KB
  __shared__ float Ws[16][WLDA];     // [k][col], 8.4 KB
  int tid = threadIdx.x;
  int r0 = blockIdx.x * 128;
  int tx = tid & 15, ty = tid >> 4;  // cols {tx*4, 64+tx*4}, rows ty*8..ty*8+7
  float acc[8][8] = {};
  for (int ks = 0; ks < 16; ++ks) {
    const float* Asrc = (ks < 8) ? agg2 : xp1;
    const float* Wsrc = (ks < 8) ? W2rel : W2root;
    int kof = (ks & 7) * 16;
    // stage A transposed: 128 rows x 16 k = 512 float4, 2/thread
#pragma unroll
    for (int l = 0; l < 2; ++l) {
      int idx = l * 256 + tid;
      int row = idx >> 2, kq = (idx & 3) * 4;
      float4 v = *(const float4*)&Asrc[(size_t)(r0 + row) * 128 + kof + kq];
      As[kq + 0][row] = v.x; As[kq + 1][row] = v.y;
      As[kq + 2][row] = v.z; As[kq + 3][row] = v.w;
    }
    // stage W: 16 k x 128 cols = 512 float4, 2/thread
#pragma unroll
    for (int l = 0; l < 2; ++l) {
      int idx = l * 256 + tid;
      int kr = idx >> 5, c4 = (idx & 31) * 4;
      *(float4*)&Ws[kr][c4] = *(const float4*)&Wsrc[(size_t)(kof + kr) * 128 + c4];
    }
    __syncthreads();
#pragma unroll 8
    for (int kk = 0; kk < 16; ++kk) {
      float4 a0 = *(const float4*)&As[kk][ty * 8];
      float4 a1 = *(const float4*)&As[kk][ty * 8 + 4];
      float4 w0 = *(const float4*)&Ws[kk][tx * 4];
      float4 w1 = *(const float4*)&Ws[kk][64 + tx * 4];
      float av[8] = {a0.x, a0.y, a0.z, a0.w, a1.x, a1.y, a1.z, a1.w};
      float wv[8] = {w0.x, w0.y, w0.z, w0.w, w1.x, w1.y, w1.z, w1.w};
#pragma unroll
      for (int i = 0; i < 8; ++i)
#pragma unroll
        for (int j = 0; j < 8; ++j) acc[i][j] += av[i] * wv[j];
    }
    __syncthreads();
  }
  float4 bb0 = *(const float4*)&b2[tx * 4];
  float4 bb1 = *(const float4*)&b2[64 + tx * 4];
  float4 pp0 = *(const float4*)&p2[tx * 4];
  float4 pp1 = *(const float4*)&p2[64 + tx * 4];
  float bbv[8] = {bb0.x, bb0.y, bb0.z, bb0.w, bb1.x, bb1.y, bb1.z, bb1.w};
  float pbv[8] = {pp0.x, pp0.y, pp0.z, pp0.w, pp1.x, pp1.y, pp1.z, pp1.w};
  float inv = invp[1];
#pragma unroll
  for (int i = 0; i < 8; ++i) {
    int row = r0 + ty * 8 + i;
    float o[8], dot = 0.f;
#pragma unroll
    for (int j = 0; j < 8; ++j) {
      o[j] = fmaxf(acc[i][j] + bbv[j], 0.f);
      dot += o[j] * pbv[j];
    }
    *(float4*)&h2[(size_t)row * 128 + tx * 4] = make_float4(o[0], o[1], o[2], o[3]);
    *(float4*)&h2[(size_t)row * 128 + 64 + tx * 4] = make_float4(o[4], o[5], o[6], o[7]);
#pragma unroll
    for (int off = 8; off > 0; off >>= 1) dot += __shfl_down(dot, off, 16);
    if (tx == 0) score2[row] = tanhf(dot * inv);
  }
}

// ---------------- target conv + relu + avgpool -> xs[t][b][o] ----------------
__global__ void k_conv(const float* __restrict__ target, const float* __restrict__ Wc,
                       const float* __restrict__ bc, float* __restrict__ xs) {
  int gb = blockIdx.x;               // B*19
  int b = gb / TSEQ, tt = gb % TSEQ;
  int o = threadIdx.x;               // 128
  __shared__ float tg[30][8];
  for (int i = threadIdx.x; i < 210; i += 128) {
    int ch = i / 7, u = i % 7;
    tg[ch][u] = target[((size_t)b * 30 + ch) * 101 + tt * 5 + u];
  }
  __syncthreads();
  const float* w = Wc + (size_t)o * 90;
  float acc5[5] = {0, 0, 0, 0, 0};
  for (int ch = 0; ch < 30; ++ch) {
    float w0 = w[ch * 3], w1 = w[ch * 3 + 1], w2 = w[ch * 3 + 2];
#pragma unroll
    for (int u = 0; u < 5; ++u)
      acc5[u] += tg[ch][u] * w0 + tg[ch][u + 1] * w1 + tg[ch][u + 2] * w2;
  }
  float bo = bc[o], s = 0.f;
#pragma unroll
  for (int u = 0; u < 5; ++u) s += fmaxf(acc5[u] + bo, 0.f);
  xs[((size_t)tt * BB + b) * 128 + o] = s * 0.2f;
}

// ---------------- gi = xs @ Wih^T + bih; 16 batches per block ----------------
#define GIB 16
__global__ __launch_bounds__(384) void k_gi(const float* __restrict__ xs,
                     const float* __restrict__ Wihf, const float* __restrict__ bihf,
                     const float* __restrict__ Wihb, const float* __restrict__ bihb,
                     float* __restrict__ gi) {
  int bg = blockIdx.x & 7;
  int t = (blockIdx.x >> 3) % TSEQ;
  int dir = blockIdx.x / (8 * TSEQ);
  int b0 = bg * GIB;
  __shared__ float xst[GIB][128];
  int tid = threadIdx.x;
  for (int i = tid; i < GIB * 128; i += 384) {
    int bb = i >> 7, k = i & 127;
    xst[bb][k] = xs[((size_t)t * BB + b0 + bb) * 128 + k];
  }
  __syncthreads();
  int j = tid;
  if (j < 360) {
    const float* W = (dir ? Wihb : Wihf) + (size_t)j * 128;
    float bias = (dir ? bihb : bihf)[j];
    float acc[GIB];
#pragma unroll
    for (int bb = 0; bb < GIB; ++bb) acc[bb] = bias;
#pragma unroll 4
    for (int k = 0; k < 128; ++k) {
      float w = W[k];
#pragma unroll
      for (int bb = 0; bb < GIB; ++bb) acc[bb] += xst[bb][k] * w;
    }
    size_t base = ((size_t)dir * TSEQ + t) * BB + b0;
#pragma unroll
    for (int bb = 0; bb < GIB; ++bb) gi[(base + bb) * 360 + j] = acc[bb];
  }
}

// ---------------- GRU recurrence: Whh rows held in REGISTERS, h via LDS broadcast ----------------
__global__ __launch_bounds__(384) void k_gru(const float* __restrict__ gi,
                      const float* __restrict__ Whhf, const float* __restrict__ bhhf,
                      const float* __restrict__ Whhb, const float* __restrict__ bhhb,
                      float* __restrict__ xc) {
  int pair = blockIdx.x & 63, dir = blockIdx.x >> 6;
  int b0 = pair * 2;
  const float* Whh = dir ? Whhb : Whhf;
  const float* bhh = dir ? bhhb : bhhf;
  __shared__ float h_sh[2][HID];
  __shared__ float g0[360], g1[360];
  int j = threadIdx.x;               // 384
  float wrow[HID];
  float bias = 0.f;
  if (j < 360) {
    const float4* W4 = (const float4*)(Whh + (size_t)j * HID);
#pragma unroll
    for (int k4 = 0; k4 < HID / 4; ++k4) {
      float4 w = W4[k4];
      wrow[k4 * 4 + 0] = w.x; wrow[k4 * 4 + 1] = w.y;
      wrow[k4 * 4 + 2] = w.z; wrow[k4 * 4 + 3] = w.w;
    }
    bias = bhh[j];
  }
  if (j < 2 * HID) h_sh[j / HID][j % HID] = 0.f;
  __syncthreads();
  for (int st = 0; st < TSEQ; ++st) {
    int tt = dir ? (TSEQ - 1 - st) : st;
    if (j < 360) {
      float a0 = bias, a1 = bias;
      const float4* h40 = (const float4*)h_sh[0];
      const float4* h41 = (const float4*)h_sh[1];
#pragma unroll
      for (int k4 = 0; k4 < HID / 4; ++k4) {
        float4 v0 = h40[k4];
        float4 v1 = h41[k4];
        a0 += wrow[k4*4+0]*v0.x + wrow[k4*4+1]*v0.y + wrow[k4*4+2]*v0.z + wrow[k4*4+3]*v0.w;
        a1 += wrow[k4*4+0]*v1.x + wrow[k4*4+1]*v1.y + wrow[k4*4+2]*v1.z + wrow[k4*4+3]*v1.w;
      }
      g0[j] = a0; g1[j] = a1;
    }
    __syncthreads();
    if (j < 2 * HID) {
      int bb = j / HID, th = j - bb * HID;
      const float* g = gi + (((size_t)dir * TSEQ + tt) * BB + (b0 + bb)) * 360;
      const float* gh = bb ? g1 : g0;
      float r  = 1.f / (1.f + expf(-(g[th]       + gh[th])));
      float z  = 1.f / (1.f + expf(-(g[120 + th] + gh[120 + th])));
      float ng = tanhf(g[240 + th] + r * gh[240 + th]);
      float hn = (1.f - z) * ng + z * h_sh[bb][th];
      h_sh[bb][th] = hn;
      xc[(size_t)(b0 + bb) * 4816 + 256 + (size_t)tt * 240 + dir * 120 + th] = hn;
    }
    __syncthreads();
  }
}

// ---------------- xg = x1 + x2 into xc[:, :256] ----------------
__global__ void k_xg(const float* __restrict__ x1, const float* __restrict__ x2,
                     float* __restrict__ xc) {
  int b = blockIdx.x, f = threadIdx.x;
  xc[(size_t)b * 4816 + f] = x1[b * 256 + f] + x2[b * 256 + f];
}

// ---------------- d1 partial GEMM ----------------
__global__ __launch_bounds__(128) void k_d1(const float* __restrict__ xc,
                                            const float* __restrict__ Wd1,
                                            float* __restrict__ part) {
  int c = blockIdx.x % D1CH;
  int rg = blockIdx.x / D1CH;
  int k0 = c * 128, kn = min(128, D1K - k0);
  __shared__ float xcs[8][128];
  int tid = threadIdx.x;
#pragma unroll
  for (int l = 0; l < 8; ++l) {
    int i = tid + l * 128;
    int r = i >> 7, k = i & 127;
    xcs[r][k] = (k < kn) ? xc[(size_t)(rg * 8 + r) * D1K + k0 + k] : 0.f;
  }
  __syncthreads();
  int j = tid;
  if (j < 102) {
    float acc[8] = {};
    for (int k = 0; k < kn; ++k) {
      float w = Wd1[(size_t)(k0 + k) * 102 + j];
#pragma unroll
      for (int r = 0; r < 8; ++r) acc[r] += xcs[r][k] * w;
    }
#pragma unroll
    for (int r = 0; r < 8; ++r)
      part[((size_t)(rg * 8 + r) * D1CH + c) * 102 + j] = acc[r];
  }
}

// ---------------- reduce partials + relu + d3 + log_softmax ----------------
__global__ void k_final2(const float* __restrict__ part, const float* __restrict__ bd1,
                         const float* __restrict__ Wd3, const float* __restrict__ bd3,
                         float* __restrict__ out) {
  __shared__ float tmp2[2];
  int b = blockIdx.x, j = threadIdx.x;
  float v = 0.f;
  if (j < 102) {
    float acc = bd1[j];
    for (int c = 0; c < D1CH; ++c) acc += part[((size_t)b * D1CH + c) * 102 + j];
    v = fmaxf(acc, 0.f);
  }
  float c0 = (j < 102) ? v * Wd3[j * 2] : 0.f;
  float c1 = (j < 102) ? v * Wd3[j * 2 + 1] : 0.f;
  float z0 = blockReduceSum128(c0, tmp2) + bd3[0];
  float z1 = blockReduceSum128(c1, tmp2) + bd3[1];
  if (j < 2) {
    float m = fmaxf(z0, z1);
    float lse = m + logf(expf(z0 - m) + expf(z1 - m));
    out[b * 2 + j] = (j == 0 ? z0 : z1) - lse;
  }
}

// ---------------- launch ----------------
extern "C" void kernel_launch(void* const* d_in, const int* in_sizes, int n_in,
                              void* d_out, int out_size, void* d_ws, size_t ws_size,
                              hipStream_t stream) {
  const float* x      = (const float*)d_in[0];
  const float* target = (const float*)d_in[1];
  const int*   esrc   = (const int*)d_in[2];
  const int*   edst   = (const int*)d_in[3];
  const float* W1rel  = (const float*)d_in[4];
  const float* W1root = (const float*)d_in[5];
  const float* b1     = (const float*)d_in[6];
  const float* p1     = (const float*)d_in[7];
  const float* W2rel  = (const float*)d_in[8];
  const float* W2root = (const float*)d_in[9];
  const float* b2     = (const float*)d_in[10];
  const float* p2     = (const float*)d_in[11];
  const float* Wc     = (const float*)d_in[12];
  const float* bc     = (const float*)d_in[13];
  const float* Wihf   = (const float*)d_in[14];
  const float* Whhf   = (const float*)d_in[15];
  const float* bihf   = (const float*)d_in[16];
  const float* bhhf   = (const float*)d_in[17];
  const float* Wihb   = (const float*)d_in[18];
  const float* Whhb   = (const float*)d_in[19];
  const float* bihb   = (const float*)d_in[20];
  const float* bhhb   = (const float*)d_in[21];
  const float* Wd1    = (const float*)d_in[22];
  const float* bd1    = (const float*)d_in[23];
  const float* Wd3    = (const float*)d_in[24];
  const float* bd3    = (const float*)d_in[25];
  float* out = (float*)d_out;

  char* wsb = (char*)d_ws;
  size_t off = 0;
  auto alloc = [&](size_t bytes) -> void* {
    void* p = wsb + off;
    off = (off + bytes + 255) & ~(size_t)255;
    return p;
  };
  float* regH    = (float*)alloc((size_t)BN * 128 * 4);   // h1 / agg2 (64MB)
  float* agg1    = (float*)alloc((size_t)BN * 4 * 4);
  float* score1  = (float*)alloc((size_t)BN * 4);
  int*   perm1   = (int*)  alloc((size_t)BB * K1C * 4);
  int*   map1    = (int*)  alloc((size_t)BN * 4);
  float* xp1     = (float*)alloc((size_t)BB * K1C * 128 * 4);
  float* h2      = (float*)alloc((size_t)BB * K1C * 128 * 4);
  float* score2  = (float*)alloc((size_t)BB * K1C * 4);
  int*   perm2   = (int*)  alloc((size_t)BB * K2C * 4);
  float* x1      = (float*)alloc((size_t)BB * 256 * 4);
  float* x2      = (float*)alloc((size_t)BB * 256 * 4);
  float* invp    = (float*)alloc(256);
  float* xs      = (float*)alloc((size_t)TSEQ * BB * 128 * 4);
  float* gi      = (float*)alloc((size_t)2 * TSEQ * BB * 360 * 4);
  float* xc      = (float*)alloc((size_t)BB * 4816 * 4);
  int*   starts1 = (int*)  alloc((size_t)BN * 4);
  int*   cnt1    = (int*)  alloc((size_t)BN * 4);
  int*   elist1  = (int*)  alloc((size_t)EDG * 4);
  int*   starts2 = (int*)  alloc((size_t)BB * K1C * 4);
  int*   cnt2    = (int*)  alloc((size_t)BB * K1C * 4);
  int*   elist2  = (int*)  alloc((size_t)EDG * 4);
  float* pmax    = (float*)alloc((size_t)BB * 13 * 128 * 4);
  float* psum    = (float*)alloc((size_t)BB * 13 * 128 * 4);
  float* part    = (float*)alloc((size_t)BB * D1CH * 102 * 4);
  float* h1   = regH;
  float* agg2 = regH;

  k_pnorm<<<1, 128, 0, stream>>>(p1, p2, invp);
  k_csr1<<<BB, 1024, 0, stream>>>(esrc, edst, starts1, cnt1, elist1);

  // --- layer 1 ---
  k_agg1<<<BB, 1024, 0, stream>>>(starts1, cnt1, elist1, x, agg1);
  k_h1<<<BN * 32 / 256, 256, 0, stream>>>(x, agg1, W1rel, W1root, b1, p1, invp, h1, score1);
  k_sort<<<BB, 512, 0, stream>>>(score1, NN, K1C, perm1, map1);
  {
    int nch = (K1C + RCH - 1) / RCH;  // 13
    k_gatherread<<<BB * nch, 128, 0, stream>>>(h1, score1, perm1, xp1, pmax, psum, K1C, nch);
    k_readout2<<<BB, 128, 0, stream>>>(pmax, psum, x1, K1C, nch);
  }

  // --- layer 2: filtered CSR + LDS-staged aggregate ---
  k_csr2<<<BB, 1024, 0, stream>>>(esrc, edst, map1, starts2, cnt2, elist2);
  k_agg2s<<<BB * 4, 1024, 0, stream>>>(starts2, cnt2, elist2, xp1, agg2);
  k_h2<<<(BB * K1C) / 128, 256, 0, stream>>>(agg2, xp1, W2rel, W2root, b2, p2, invp, h2, score2);
  k_sort<<<BB, 512, 0, stream>>>(score2, K1C, K2C, perm2, nullptr);
  {
    int nch = (K2C + RCH - 1) / RCH;  // 11
    k_gatherread<<<BB * nch, 128, 0, stream>>>(h2, score2, perm2, nullptr, pmax, psum, K2C, nch);
    k_readout2<<<BB, 128, 0, stream>>>(pmax, psum, x2, K2C, nch);
  }

  // --- target branch ---
  k_conv<<<BB * TSEQ, 128, 0, stream>>>(target, Wc, bc, xs);
  k_gi<<<2 * TSEQ * 8, 384, 0, stream>>>(xs, Wihf, bihf, Wihb, bihb, gi);
  k_gru<<<2 * 64, 384, 0, stream>>>(gi, Whhf, bhhf, Whhb, bhhb, xc);

  // --- head ---
  k_xg<<<BB, 256, 0, stream>>>(x1, x2, xc);
  k_d1<<<(BB / 8) * D1CH, 128, 0, stream>>>(xc, Wd1, part);
  k_final2<<<BB, 128, 0, stream>>>(part, bd1, Wd3, bd3, out);
}